// Round 1
// baseline (1374.279 us; speedup 1.0000x reference)
//
#include <hip/hip_runtime.h>

namespace {

constexpr int NP = 100000;
constexpr int NS = 10000;
constexpr int EC = 1600000;
constexpr int LC = 1000000;

// ---------------- CSR build ----------------

__global__ void k_hist(const int* __restrict__ src, const int* __restrict__ dst,
                       int* __restrict__ deg_pd, int* __restrict__ deg_se, int E) {
  int i = blockIdx.x * blockDim.x + threadIdx.x;
  if (i < E) {
    atomicAdd(&deg_se[dst[i]], 1);
    atomicAdd(&deg_pd[src[i]], 1);
  }
}

__global__ void k_blocksum(const int* __restrict__ deg, int n, int* __restrict__ blksum) {
  __shared__ int sd[256];
  int t = threadIdx.x;
  int idx = blockIdx.x * 256 + t;
  sd[t] = (idx < n) ? deg[idx] : 0;
  __syncthreads();
  for (int off = 128; off > 0; off >>= 1) {
    if (t < off) sd[t] += sd[t + off];
    __syncthreads();
  }
  if (t == 0) blksum[blockIdx.x] = sd[0];
}

// single block, 1024 threads; nb <= 1024. In-place exclusive scan.
__global__ void k_scan_blk(int* __restrict__ blksum, int nb) {
  __shared__ int sd[1024];
  int t = threadIdx.x;
  int orig = (t < nb) ? blksum[t] : 0;
  sd[t] = orig;
  __syncthreads();
  for (int off = 1; off < 1024; off <<= 1) {
    int u = (t >= off) ? sd[t - off] : 0;
    __syncthreads();
    sd[t] += u;
    __syncthreads();
  }
  if (t < nb) blksum[t] = sd[t] - orig;  // exclusive
}

__global__ void k_scan_final(const int* __restrict__ deg, int n, const int* __restrict__ blkoff,
                             int* __restrict__ rowptr, int* __restrict__ cursor) {
  __shared__ int sd[256];
  int t = threadIdx.x;
  int idx = blockIdx.x * 256 + t;
  int orig = (idx < n) ? deg[idx] : 0;
  sd[t] = orig;
  __syncthreads();
  for (int off = 1; off < 256; off <<= 1) {
    int u = (t >= off) ? sd[t - off] : 0;
    __syncthreads();
    sd[t] += u;
    __syncthreads();
  }
  if (idx < n) {
    int v = sd[t] - orig + blkoff[blockIdx.x];
    rowptr[idx] = v;
    cursor[idx] = v;
  }
}

__global__ void k_fill(const int* __restrict__ src, const int* __restrict__ dst,
                       int* __restrict__ cur_se, int* __restrict__ cur_pd,
                       int* __restrict__ col_se, int* __restrict__ col_pd, int E) {
  int i = blockIdx.x * blockDim.x + threadIdx.x;
  if (i < E) {
    int s = src[i], d = dst[i];
    int p = atomicAdd(&cur_se[d], 1);
    col_se[p] = s;                 // neighbor (pd id) grouped by se dst
    int q = atomicAdd(&cur_pd[s], 1);
    col_pd[q] = d;                 // neighbor (se id) grouped by pd src
  }
}

// ---------------- input projection: out = x @ W + b + emb[nid] ----------------
// 16 rows per 256-thread block; each thread: 1 output col (n = t&63), 4 rows.

template <int K>
__global__ void __launch_bounds__(256) k_proj(const float* __restrict__ x,
                                              const float* __restrict__ W,
                                              const float* __restrict__ b,
                                              const float* __restrict__ emb,
                                              const int* __restrict__ nid,
                                              float* __restrict__ out, int M) {
  __shared__ float xs[16 * K];
  const int t = threadIdx.x;
  const int row0 = blockIdx.x * 16;
  {
    const float4* xin = reinterpret_cast<const float4*>(x + (size_t)row0 * K);
    float4* xs4 = reinterpret_cast<float4*>(xs);
    constexpr int T4 = 16 * K / 4;
#pragma unroll
    for (int j = t; j < T4; j += 256) xs4[j] = xin[j];
  }
  __syncthreads();
  const int n = t & 63;
  const int mg = t >> 6;  // wave id = row offset 0..3
  float acc0 = 0.f, acc1 = 0.f, acc2 = 0.f, acc3 = 0.f;
  for (int k = 0; k < K; k += 4) {
    const float w0 = W[(k + 0) * 64 + n];
    const float w1 = W[(k + 1) * 64 + n];
    const float w2 = W[(k + 2) * 64 + n];
    const float w3 = W[(k + 3) * 64 + n];
    float4 v;
    v = *reinterpret_cast<const float4*>(&xs[(mg + 0) * K + k]);
    acc0 += v.x * w0 + v.y * w1 + v.z * w2 + v.w * w3;
    v = *reinterpret_cast<const float4*>(&xs[(mg + 4) * K + k]);
    acc1 += v.x * w0 + v.y * w1 + v.z * w2 + v.w * w3;
    v = *reinterpret_cast<const float4*>(&xs[(mg + 8) * K + k]);
    acc2 += v.x * w0 + v.y * w1 + v.z * w2 + v.w * w3;
    v = *reinterpret_cast<const float4*>(&xs[(mg + 12) * K + k]);
    acc3 += v.x * w0 + v.y * w1 + v.z * w2 + v.w * w3;
  }
  const float bias = b[n];
  int r;
  r = row0 + mg + 0;
  if (r < M) out[(size_t)r * 64 + n] = acc0 + bias + emb[(size_t)nid[r] * 64 + n];
  r = row0 + mg + 4;
  if (r < M) out[(size_t)r * 64 + n] = acc1 + bias + emb[(size_t)nid[r] * 64 + n];
  r = row0 + mg + 8;
  if (r < M) out[(size_t)r * 64 + n] = acc2 + bias + emb[(size_t)nid[r] * 64 + n];
  r = row0 + mg + 12;
  if (r < M) out[(size_t)r * 64 + n] = acc3 + bias + emb[(size_t)nid[r] * 64 + n];
}

// ---------------- aggregation: mean over CSR neighbors ----------------
// one wave per dst node, lane = channel

__global__ void __launch_bounds__(256) k_agg(const float* __restrict__ h,
                                             const int* __restrict__ rowptr,
                                             const int* __restrict__ deg,
                                             const int* __restrict__ col,
                                             float* __restrict__ mean, int n_dst) {
  const int node = blockIdx.x * 4 + (threadIdx.x >> 6);
  const int lane = threadIdx.x & 63;
  if (node >= n_dst) return;
  const int beg = rowptr[node];
  const int cnt = deg[node];
  float acc = 0.f;
  int j = 0;
  for (; j + 4 <= cnt; j += 4) {
    const int n0 = col[beg + j + 0];
    const int n1 = col[beg + j + 1];
    const int n2 = col[beg + j + 2];
    const int n3 = col[beg + j + 3];
    const float a0 = h[(size_t)n0 * 64 + lane];
    const float a1 = h[(size_t)n1 * 64 + lane];
    const float a2 = h[(size_t)n2 * 64 + lane];
    const float a3 = h[(size_t)n3 * 64 + lane];
    acc += a0 + a1 + a2 + a3;
  }
  for (; j < cnt; ++j) acc += h[(size_t)col[beg + j] * 64 + lane];
  const float d = (cnt > 0) ? (float)cnt : 1.f;
  mean[(size_t)node * 64 + lane] = acc / d;
}

// ---------------- combine: out = act(mean @ Wl + bl + xd @ Wr) ----------------

template <bool RELU>
__global__ void __launch_bounds__(256) k_combine(const float* __restrict__ mean,
                                                 const float* __restrict__ xd,
                                                 const float* __restrict__ Wl,
                                                 const float* __restrict__ bl,
                                                 const float* __restrict__ Wr,
                                                 float* __restrict__ out, int M) {
  __shared__ float wls[64 * 64];
  __shared__ float wrs[64 * 64];
  __shared__ float ms[16 * 64];
  __shared__ float xs[16 * 64];
  const int t = threadIdx.x;
  {
    const float4* wl4 = reinterpret_cast<const float4*>(Wl);
    const float4* wr4 = reinterpret_cast<const float4*>(Wr);
    float4* a = reinterpret_cast<float4*>(wls);
    float4* c = reinterpret_cast<float4*>(wrs);
#pragma unroll
    for (int j = t; j < 1024; j += 256) {
      a[j] = wl4[j];
      c[j] = wr4[j];
    }
  }
  const int row0 = blockIdx.x * 16;
  reinterpret_cast<float4*>(ms)[t] =
      reinterpret_cast<const float4*>(mean + (size_t)row0 * 64)[t];
  reinterpret_cast<float4*>(xs)[t] =
      reinterpret_cast<const float4*>(xd + (size_t)row0 * 64)[t];
  __syncthreads();
  const int n = t & 63;
  const int mg = t >> 6;
  float acc0 = 0.f, acc1 = 0.f, acc2 = 0.f, acc3 = 0.f;
  for (int k = 0; k < 64; k += 4) {
    const float wl0 = wls[(k + 0) * 64 + n];
    const float wl1 = wls[(k + 1) * 64 + n];
    const float wl2 = wls[(k + 2) * 64 + n];
    const float wl3 = wls[(k + 3) * 64 + n];
    const float wr0 = wrs[(k + 0) * 64 + n];
    const float wr1 = wrs[(k + 1) * 64 + n];
    const float wr2 = wrs[(k + 2) * 64 + n];
    const float wr3 = wrs[(k + 3) * 64 + n];
    float4 mv, xv;
    mv = *reinterpret_cast<const float4*>(&ms[(mg + 0) * 64 + k]);
    xv = *reinterpret_cast<const float4*>(&xs[(mg + 0) * 64 + k]);
    acc0 += mv.x * wl0 + mv.y * wl1 + mv.z * wl2 + mv.w * wl3 + xv.x * wr0 + xv.y * wr1 +
            xv.z * wr2 + xv.w * wr3;
    mv = *reinterpret_cast<const float4*>(&ms[(mg + 4) * 64 + k]);
    xv = *reinterpret_cast<const float4*>(&xs[(mg + 4) * 64 + k]);
    acc1 += mv.x * wl0 + mv.y * wl1 + mv.z * wl2 + mv.w * wl3 + xv.x * wr0 + xv.y * wr1 +
            xv.z * wr2 + xv.w * wr3;
    mv = *reinterpret_cast<const float4*>(&ms[(mg + 8) * 64 + k]);
    xv = *reinterpret_cast<const float4*>(&xs[(mg + 8) * 64 + k]);
    acc2 += mv.x * wl0 + mv.y * wl1 + mv.z * wl2 + mv.w * wl3 + xv.x * wr0 + xv.y * wr1 +
            xv.z * wr2 + xv.w * wr3;
    mv = *reinterpret_cast<const float4*>(&ms[(mg + 12) * 64 + k]);
    xv = *reinterpret_cast<const float4*>(&xs[(mg + 12) * 64 + k]);
    acc3 += mv.x * wl0 + mv.y * wl1 + mv.z * wl2 + mv.w * wl3 + xv.x * wr0 + xv.y * wr1 +
            xv.z * wr2 + xv.w * wr3;
  }
  const float bias = bl[n];
  float v;
  v = acc0 + bias; if (RELU) v = fmaxf(v, 0.f); out[(size_t)(row0 + mg + 0) * 64 + n] = v;
  v = acc1 + bias; if (RELU) v = fmaxf(v, 0.f); out[(size_t)(row0 + mg + 4) * 64 + n] = v;
  v = acc2 + bias; if (RELU) v = fmaxf(v, 0.f); out[(size_t)(row0 + mg + 8) * 64 + n] = v;
  v = acc3 + bias; if (RELU) v = fmaxf(v, 0.f); out[(size_t)(row0 + mg + 12) * 64 + n] = v;
}

// ---------------- classifier: pred[e] = dot(pd2[i0[e]], se2[i1[e]]) ----------------
// 16 lanes per edge, float4 loads, shfl_xor reduce within 16

__global__ void __launch_bounds__(256) k_classify(const float* __restrict__ pd2,
                                                  const float* __restrict__ se2,
                                                  const int* __restrict__ i0,
                                                  const int* __restrict__ i1,
                                                  float* __restrict__ pred, int L) {
  const int e = blockIdx.x * 16 + (threadIdx.x >> 4);
  if (e >= L) return;
  const int l16 = threadIdx.x & 15;
  const int a = i0[e];
  const int b = i1[e];
  const float4 va = *reinterpret_cast<const float4*>(&pd2[(size_t)a * 64 + l16 * 4]);
  const float4 vb = *reinterpret_cast<const float4*>(&se2[(size_t)b * 64 + l16 * 4]);
  float v = va.x * vb.x + va.y * vb.y + va.z * vb.z + va.w * vb.w;
  v += __shfl_xor(v, 1, 16);
  v += __shfl_xor(v, 2, 16);
  v += __shfl_xor(v, 4, 16);
  v += __shfl_xor(v, 8, 16);
  if (l16 == 0) pred[e] = v;
}

__global__ void k_copy4(const float4* __restrict__ src, float4* __restrict__ dst, int n4) {
  int i = blockIdx.x * blockDim.x + threadIdx.x;
  if (i < n4) dst[i] = src[i];
}

}  // namespace

extern "C" void kernel_launch(void* const* d_in, const int* in_sizes, int n_in,
                              void* d_out, int out_size, void* d_ws, size_t ws_size,
                              hipStream_t stream) {
  (void)in_sizes; (void)n_in; (void)out_size; (void)ws_size;
  const float* x_pd = (const float*)d_in[0];
  const float* x_se = (const float*)d_in[1];
  const int* nid_pd = (const int*)d_in[2];
  const int* nid_se = (const int*)d_in[3];
  const int* eidx = (const int*)d_in[4];
  const int* elidx = (const int*)d_in[5];
  const float* elabel = (const float*)d_in[6];
  const float* W_pd = (const float*)d_in[7];
  const float* b_pd = (const float*)d_in[8];
  const float* W_se = (const float*)d_in[9];
  const float* b_se = (const float*)d_in[10];
  const float* emb_pd = (const float*)d_in[11];
  const float* emb_se = (const float*)d_in[12];
  const float* c1_p2s_Wl = (const float*)d_in[13];
  const float* c1_p2s_bl = (const float*)d_in[14];
  const float* c1_p2s_Wr = (const float*)d_in[15];
  const float* c1_s2p_Wl = (const float*)d_in[16];
  const float* c1_s2p_bl = (const float*)d_in[17];
  const float* c1_s2p_Wr = (const float*)d_in[18];
  const float* c2_p2s_Wl = (const float*)d_in[19];
  const float* c2_p2s_bl = (const float*)d_in[20];
  const float* c2_p2s_Wr = (const float*)d_in[21];
  const float* c2_s2p_Wl = (const float*)d_in[22];
  const float* c2_s2p_bl = (const float*)d_in[23];
  const float* c2_s2p_Wr = (const float*)d_in[24];

  const int* src = eidx;       // pd ids
  const int* dst = eidx + EC;  // se ids
  const int* li0 = elidx;      // pd ids
  const int* li1 = elidx + LC; // se ids

  char* ws = (char*)d_ws;
  size_t o = 0;
  auto alloc = [&](size_t bytes) -> char* {
    char* p = ws + o;
    o = (o + bytes + 255) & ~(size_t)255;
    return p;
  };
  float* h_pd = (float*)alloc((size_t)NP * 64 * 4);  // reused as pd2 in layer 2
  float* h_se = (float*)alloc((size_t)NS * 64 * 4);  // reused as se2 in layer 2
  float* pd1 = (float*)alloc((size_t)NP * 64 * 4);
  float* se1 = (float*)alloc((size_t)NS * 64 * 4);
  float* agg_pd = (float*)alloc((size_t)NP * 64 * 4);
  float* agg_se = (float*)alloc((size_t)NS * 64 * 4);
  int* col_se = (int*)alloc((size_t)EC * 4);
  int* col_pd = (int*)alloc((size_t)EC * 4);
  int* deg_se = (int*)alloc((size_t)NS * 4);
  int* deg_pd = (int*)alloc((size_t)NP * 4);
  int* rp_se = (int*)alloc((size_t)NS * 4);
  int* rp_pd = (int*)alloc((size_t)NP * 4);
  int* cur_se = (int*)alloc((size_t)NS * 4);
  int* cur_pd = (int*)alloc((size_t)NP * 4);
  int* blk_se = (int*)alloc(4096);
  int* blk_pd = (int*)alloc(4096);

  hipMemsetAsync(deg_se, 0, (size_t)NS * 4, stream);
  hipMemsetAsync(deg_pd, 0, (size_t)NP * 4, stream);

  // CSR build (shared by both layers)
  k_hist<<<(EC + 255) / 256, 256, 0, stream>>>(src, dst, deg_pd, deg_se, EC);
  const int nbS = (NS + 255) / 256;  // 40
  const int nbP = (NP + 255) / 256;  // 391
  k_blocksum<<<nbS, 256, 0, stream>>>(deg_se, NS, blk_se);
  k_blocksum<<<nbP, 256, 0, stream>>>(deg_pd, NP, blk_pd);
  k_scan_blk<<<1, 1024, 0, stream>>>(blk_se, nbS);
  k_scan_blk<<<1, 1024, 0, stream>>>(blk_pd, nbP);
  k_scan_final<<<nbS, 256, 0, stream>>>(deg_se, NS, blk_se, rp_se, cur_se);
  k_scan_final<<<nbP, 256, 0, stream>>>(deg_pd, NP, blk_pd, rp_pd, cur_pd);
  k_fill<<<(EC + 255) / 256, 256, 0, stream>>>(src, dst, cur_se, cur_pd, col_se, col_pd, EC);

  // input projections
  k_proj<512><<<NP / 16, 256, 0, stream>>>(x_pd, W_pd, b_pd, emb_pd, nid_pd, h_pd, NP);
  k_proj<768><<<NS / 16, 256, 0, stream>>>(x_se, W_se, b_se, emb_se, nid_se, h_se, NS);

  // layer 1 (relu)
  k_agg<<<(NS + 3) / 4, 256, 0, stream>>>(h_pd, rp_se, deg_se, col_se, agg_se, NS);
  k_combine<true><<<NS / 16, 256, 0, stream>>>(agg_se, h_se, c1_p2s_Wl, c1_p2s_bl,
                                               c1_p2s_Wr, se1, NS);
  k_agg<<<(NP + 3) / 4, 256, 0, stream>>>(h_se, rp_pd, deg_pd, col_pd, agg_pd, NP);
  k_combine<true><<<NP / 16, 256, 0, stream>>>(agg_pd, h_pd, c1_s2p_Wl, c1_s2p_bl,
                                               c1_s2p_Wr, pd1, NP);

  // layer 2 (no act); outputs alias h buffers (h_pd/h_se dead after layer 1)
  float* se2 = h_se;
  float* pd2 = h_pd;
  k_agg<<<(NS + 3) / 4, 256, 0, stream>>>(pd1, rp_se, deg_se, col_se, agg_se, NS);
  k_combine<false><<<NS / 16, 256, 0, stream>>>(agg_se, se1, c2_p2s_Wl, c2_p2s_bl,
                                                c2_p2s_Wr, se2, NS);
  k_agg<<<(NP + 3) / 4, 256, 0, stream>>>(se1, rp_pd, deg_pd, col_pd, agg_pd, NP);
  k_combine<false><<<NP / 16, 256, 0, stream>>>(agg_pd, pd1, c2_s2p_Wl, c2_s2p_bl,
                                                c2_s2p_Wr, pd2, NP);

  // classifier + label passthrough
  float* outF = (float*)d_out;
  k_classify<<<(LC + 15) / 16, 256, 0, stream>>>(pd2, se2, li0, li1, outF, LC);
  k_copy4<<<(LC / 4 + 255) / 256, 256, 0, stream>>>((const float4*)elabel,
                                                    (float4*)(outF + LC), LC / 4);
}

// Round 2
// 1023.061 us; speedup vs baseline: 1.3433x; 1.3433x over previous
//
#include <hip/hip_runtime.h>

namespace {

constexpr int NP = 100000;
constexpr int NS = 10000;
constexpr int EC = 1600000;
constexpr int LC = 1000000;

// bucketed CSR build params
constexpr int SH_S = 6;                        // se nodes per bucket = 64
constexpr int SH_P = 9;                        // pd nodes per bucket = 512
constexpr int NBS = (NS + 63) >> SH_S;         // 157 buckets
constexpr int NBP = (NP + 511) >> SH_P;        // 196 buckets
constexpr int CHUNK = 8192;
constexpr int NBLK = (EC + CHUNK - 1) / CHUNK; // 196

// ---------------- CSR build: bucketed counting sort ----------------

__global__ void __launch_bounds__(256) k_bcount(const int* __restrict__ src,
                                                const int* __restrict__ dst,
                                                int* __restrict__ bcntS,
                                                int* __restrict__ bcntP, int E) {
  __shared__ int hS[256];
  __shared__ int hP[256];
  const int t = threadIdx.x;
  hS[t] = 0;
  hP[t] = 0;
  __syncthreads();
  const int base = blockIdx.x * CHUNK;
  const int end = min(base + CHUNK, E);
  for (int e = base + t; e < end; e += 256) {
    atomicAdd(&hS[dst[e] >> SH_S], 1);
    atomicAdd(&hP[src[e] >> SH_P], 1);
  }
  __syncthreads();
  if (t < NBS && hS[t]) atomicAdd(&bcntS[t], hS[t]);
  if (t < NBP && hP[t]) atomicAdd(&bcntP[t], hP[t]);
}

// one block, 256 threads: exclusive-scan both bucket-count arrays
__global__ void __launch_bounds__(256) k_bscan(const int* __restrict__ bcntS,
                                               const int* __restrict__ bcntP,
                                               int* __restrict__ gbaseS,
                                               int* __restrict__ gbaseP,
                                               int* __restrict__ gcurS,
                                               int* __restrict__ gcurP) {
  __shared__ int s[256];
  const int t = threadIdx.x;
  int v = (t < NBS) ? bcntS[t] : 0;
  s[t] = v;
  __syncthreads();
  for (int off = 1; off < 256; off <<= 1) {
    int u = (t >= off) ? s[t - off] : 0;
    __syncthreads();
    s[t] += u;
    __syncthreads();
  }
  if (t < NBS) {
    int ex = s[t] - v;
    gbaseS[t] = ex;
    gcurS[t] = ex;
  }
  __syncthreads();
  v = (t < NBP) ? bcntP[t] : 0;
  s[t] = v;
  __syncthreads();
  for (int off = 1; off < 256; off <<= 1) {
    int u = (t >= off) ? s[t - off] : 0;
    __syncthreads();
    s[t] += u;
    __syncthreads();
  }
  if (t < NBP) {
    int ex = s[t] - v;
    gbaseP[t] = ex;
    gcurP[t] = ex;
  }
}

// scatter edges into bucket-grouped (node, nbr) pair arrays
__global__ void __launch_bounds__(256) k_bscatter(const int* __restrict__ src,
                                                  const int* __restrict__ dst,
                                                  int* __restrict__ gcurS,
                                                  int* __restrict__ gcurP,
                                                  int2* __restrict__ tmpS,
                                                  int2* __restrict__ tmpP, int E) {
  __shared__ int hS[256];
  __shared__ int hP[256];
  const int t = threadIdx.x;
  hS[t] = 0;
  hP[t] = 0;
  __syncthreads();
  const int base = blockIdx.x * CHUNK;
  const int end = min(base + CHUNK, E);
  for (int e = base + t; e < end; e += 256) {
    atomicAdd(&hS[dst[e] >> SH_S], 1);
    atomicAdd(&hP[src[e] >> SH_P], 1);
  }
  __syncthreads();
  int myBaseS = 0, myBaseP = 0;
  if (t < NBS) {
    int c = hS[t];
    myBaseS = c ? atomicAdd(&gcurS[t], c) : 0;
  }
  if (t < NBP) {
    int c = hP[t];
    myBaseP = c ? atomicAdd(&gcurP[t], c) : 0;
  }
  __syncthreads();
  if (t < NBS) hS[t] = myBaseS;  // reuse as local cursors
  if (t < NBP) hP[t] = myBaseP;
  __syncthreads();
  for (int e = base + t; e < end; e += 256) {
    const int d = dst[e];
    const int s = src[e];
    int p = atomicAdd(&hS[d >> SH_S], 1);
    tmpS[p] = make_int2(d, s);
    int q = atomicAdd(&hP[s >> SH_P], 1);
    tmpP[q] = make_int2(s, d);
  }
}

// one block per bucket: per-node histogram + LDS scan -> rowptr/deg,
// then LDS-cursor scatter of col within the bucket's L2-resident window.
template <int NN>  // nodes per bucket (64 or 512)
__global__ void __launch_bounds__(256) k_bfinal(const int2* __restrict__ tmp,
                                                const int* __restrict__ gbase,
                                                const int* __restrict__ bcnt,
                                                int shift, int Nnodes,
                                                int* __restrict__ rowptr,
                                                int* __restrict__ deg,
                                                int* __restrict__ col) {
  __shared__ int ldeg[NN];
  __shared__ int lscan[512];
  const int b = blockIdx.x;
  const int t = threadIdx.x;
  const int n0 = b << shift;
  const int base = gbase[b];
  const int cnt = bcnt[b];
  for (int i = t; i < NN; i += 256) ldeg[i] = 0;
  __syncthreads();
  for (int j = t; j < cnt; j += 256) atomicAdd(&ldeg[tmp[base + j].x - n0], 1);
  __syncthreads();
  for (int i = t; i < 512; i += 256) lscan[i] = (i < NN) ? ldeg[i] : 0;
  __syncthreads();
  for (int off = 1; off < 512; off <<= 1) {
    const int i0 = t, i1 = t + 256;
    const int v0 = (i0 >= off) ? lscan[i0 - off] : 0;
    const int v1 = (i1 >= off) ? lscan[i1 - off] : 0;
    __syncthreads();
    lscan[i0] += v0;
    lscan[i1] += v1;
    __syncthreads();
  }
  // lscan is now inclusive scan of ldeg
  for (int i = t; i < NN; i += 256) {
    const int n = n0 + i;
    if (n < Nnodes) {
      const int dg = ldeg[i];
      rowptr[n] = base + lscan[i] - dg;
      deg[n] = dg;
    }
  }
  __syncthreads();
  for (int i = t; i < NN; i += 256) lscan[i] -= ldeg[i];  // -> exclusive = cursor
  __syncthreads();
  for (int j = t; j < cnt; j += 256) {
    const int2 pr = tmp[base + j];
    const int p = atomicAdd(&lscan[pr.x - n0], 1);
    col[base + p] = pr.y;
  }
}

// ---------------- input projection: out = x @ W + b + emb[nid] ----------------

template <int K>
__global__ void __launch_bounds__(256) k_proj(const float* __restrict__ x,
                                              const float* __restrict__ W,
                                              const float* __restrict__ b,
                                              const float* __restrict__ emb,
                                              const int* __restrict__ nid,
                                              float* __restrict__ out, int M) {
  __shared__ float xs[16 * K];
  const int t = threadIdx.x;
  const int row0 = blockIdx.x * 16;
  {
    const float4* xin = reinterpret_cast<const float4*>(x + (size_t)row0 * K);
    float4* xs4 = reinterpret_cast<float4*>(xs);
    constexpr int T4 = 16 * K / 4;
#pragma unroll
    for (int j = t; j < T4; j += 256) xs4[j] = xin[j];
  }
  __syncthreads();
  const int n = t & 63;
  const int mg = t >> 6;  // wave id = row offset 0..3
  float acc0 = 0.f, acc1 = 0.f, acc2 = 0.f, acc3 = 0.f;
  for (int k = 0; k < K; k += 4) {
    const float w0 = W[(k + 0) * 64 + n];
    const float w1 = W[(k + 1) * 64 + n];
    const float w2 = W[(k + 2) * 64 + n];
    const float w3 = W[(k + 3) * 64 + n];
    float4 v;
    v = *reinterpret_cast<const float4*>(&xs[(mg + 0) * K + k]);
    acc0 += v.x * w0 + v.y * w1 + v.z * w2 + v.w * w3;
    v = *reinterpret_cast<const float4*>(&xs[(mg + 4) * K + k]);
    acc1 += v.x * w0 + v.y * w1 + v.z * w2 + v.w * w3;
    v = *reinterpret_cast<const float4*>(&xs[(mg + 8) * K + k]);
    acc2 += v.x * w0 + v.y * w1 + v.z * w2 + v.w * w3;
    v = *reinterpret_cast<const float4*>(&xs[(mg + 12) * K + k]);
    acc3 += v.x * w0 + v.y * w1 + v.z * w2 + v.w * w3;
  }
  const float bias = b[n];
  int r;
  r = row0 + mg + 0;
  if (r < M) out[(size_t)r * 64 + n] = acc0 + bias + emb[(size_t)nid[r] * 64 + n];
  r = row0 + mg + 4;
  if (r < M) out[(size_t)r * 64 + n] = acc1 + bias + emb[(size_t)nid[r] * 64 + n];
  r = row0 + mg + 8;
  if (r < M) out[(size_t)r * 64 + n] = acc2 + bias + emb[(size_t)nid[r] * 64 + n];
  r = row0 + mg + 12;
  if (r < M) out[(size_t)r * 64 + n] = acc3 + bias + emb[(size_t)nid[r] * 64 + n];
}

// ---------------- aggregation: mean over CSR neighbors ----------------
// one wave per dst node, lane = channel, 8 outstanding gathers

__global__ void __launch_bounds__(256) k_agg(const float* __restrict__ h,
                                             const int* __restrict__ rowptr,
                                             const int* __restrict__ deg,
                                             const int* __restrict__ col,
                                             float* __restrict__ mean, int n_dst) {
  const int node = blockIdx.x * 4 + (threadIdx.x >> 6);
  const int lane = threadIdx.x & 63;
  if (node >= n_dst) return;
  const int beg = rowptr[node];
  const int cnt = deg[node];
  float acc = 0.f;
  int j = 0;
  for (; j + 8 <= cnt; j += 8) {
    int n0 = col[beg + j + 0], n1 = col[beg + j + 1];
    int n2 = col[beg + j + 2], n3 = col[beg + j + 3];
    int n4 = col[beg + j + 4], n5 = col[beg + j + 5];
    int n6 = col[beg + j + 6], n7 = col[beg + j + 7];
    float a0 = h[(size_t)n0 * 64 + lane];
    float a1 = h[(size_t)n1 * 64 + lane];
    float a2 = h[(size_t)n2 * 64 + lane];
    float a3 = h[(size_t)n3 * 64 + lane];
    float a4 = h[(size_t)n4 * 64 + lane];
    float a5 = h[(size_t)n5 * 64 + lane];
    float a6 = h[(size_t)n6 * 64 + lane];
    float a7 = h[(size_t)n7 * 64 + lane];
    acc += ((a0 + a1) + (a2 + a3)) + ((a4 + a5) + (a6 + a7));
  }
  for (; j < cnt; ++j) acc += h[(size_t)col[beg + j] * 64 + lane];
  const float d = (cnt > 0) ? (float)cnt : 1.f;
  mean[(size_t)node * 64 + lane] = acc / d;
}

// ---------------- combine: out = act(mean @ Wl + bl + xd @ Wr) ----------------

template <bool RELU>
__global__ void __launch_bounds__(256) k_combine(const float* __restrict__ mean,
                                                 const float* __restrict__ xd,
                                                 const float* __restrict__ Wl,
                                                 const float* __restrict__ bl,
                                                 const float* __restrict__ Wr,
                                                 float* __restrict__ out, int M) {
  __shared__ float wls[64 * 64];
  __shared__ float wrs[64 * 64];
  __shared__ float ms[16 * 64];
  __shared__ float xs[16 * 64];
  const int t = threadIdx.x;
  {
    const float4* wl4 = reinterpret_cast<const float4*>(Wl);
    const float4* wr4 = reinterpret_cast<const float4*>(Wr);
    float4* a = reinterpret_cast<float4*>(wls);
    float4* c = reinterpret_cast<float4*>(wrs);
#pragma unroll
    for (int j = t; j < 1024; j += 256) {
      a[j] = wl4[j];
      c[j] = wr4[j];
    }
  }
  const int row0 = blockIdx.x * 16;
  reinterpret_cast<float4*>(ms)[t] =
      reinterpret_cast<const float4*>(mean + (size_t)row0 * 64)[t];
  reinterpret_cast<float4*>(xs)[t] =
      reinterpret_cast<const float4*>(xd + (size_t)row0 * 64)[t];
  __syncthreads();
  const int n = t & 63;
  const int mg = t >> 6;
  float acc0 = 0.f, acc1 = 0.f, acc2 = 0.f, acc3 = 0.f;
  for (int k = 0; k < 64; k += 4) {
    const float wl0 = wls[(k + 0) * 64 + n];
    const float wl1 = wls[(k + 1) * 64 + n];
    const float wl2 = wls[(k + 2) * 64 + n];
    const float wl3 = wls[(k + 3) * 64 + n];
    const float wr0 = wrs[(k + 0) * 64 + n];
    const float wr1 = wrs[(k + 1) * 64 + n];
    const float wr2 = wrs[(k + 2) * 64 + n];
    const float wr3 = wrs[(k + 3) * 64 + n];
    float4 mv, xv;
    mv = *reinterpret_cast<const float4*>(&ms[(mg + 0) * 64 + k]);
    xv = *reinterpret_cast<const float4*>(&xs[(mg + 0) * 64 + k]);
    acc0 += mv.x * wl0 + mv.y * wl1 + mv.z * wl2 + mv.w * wl3 + xv.x * wr0 + xv.y * wr1 +
            xv.z * wr2 + xv.w * wr3;
    mv = *reinterpret_cast<const float4*>(&ms[(mg + 4) * 64 + k]);
    xv = *reinterpret_cast<const float4*>(&xs[(mg + 4) * 64 + k]);
    acc1 += mv.x * wl0 + mv.y * wl1 + mv.z * wl2 + mv.w * wl3 + xv.x * wr0 + xv.y * wr1 +
            xv.z * wr2 + xv.w * wr3;
    mv = *reinterpret_cast<const float4*>(&ms[(mg + 8) * 64 + k]);
    xv = *reinterpret_cast<const float4*>(&xs[(mg + 8) * 64 + k]);
    acc2 += mv.x * wl0 + mv.y * wl1 + mv.z * wl2 + mv.w * wl3 + xv.x * wr0 + xv.y * wr1 +
            xv.z * wr2 + xv.w * wr3;
    mv = *reinterpret_cast<const float4*>(&ms[(mg + 12) * 64 + k]);
    xv = *reinterpret_cast<const float4*>(&xs[(mg + 12) * 64 + k]);
    acc3 += mv.x * wl0 + mv.y * wl1 + mv.z * wl2 + mv.w * wl3 + xv.x * wr0 + xv.y * wr1 +
            xv.z * wr2 + xv.w * wr3;
  }
  const float bias = bl[n];
  float v;
  v = acc0 + bias; if (RELU) v = fmaxf(v, 0.f); out[(size_t)(row0 + mg + 0) * 64 + n] = v;
  v = acc1 + bias; if (RELU) v = fmaxf(v, 0.f); out[(size_t)(row0 + mg + 4) * 64 + n] = v;
  v = acc2 + bias; if (RELU) v = fmaxf(v, 0.f); out[(size_t)(row0 + mg + 8) * 64 + n] = v;
  v = acc3 + bias; if (RELU) v = fmaxf(v, 0.f); out[(size_t)(row0 + mg + 12) * 64 + n] = v;
}

// ---------------- classifier ----------------

__global__ void __launch_bounds__(256) k_classify(const float* __restrict__ pd2,
                                                  const float* __restrict__ se2,
                                                  const int* __restrict__ i0,
                                                  const int* __restrict__ i1,
                                                  float* __restrict__ pred, int L) {
  const int e = blockIdx.x * 16 + (threadIdx.x >> 4);
  if (e >= L) return;
  const int l16 = threadIdx.x & 15;
  const int a = i0[e];
  const int b = i1[e];
  const float4 va = *reinterpret_cast<const float4*>(&pd2[(size_t)a * 64 + l16 * 4]);
  const float4 vb = *reinterpret_cast<const float4*>(&se2[(size_t)b * 64 + l16 * 4]);
  float v = va.x * vb.x + va.y * vb.y + va.z * vb.z + va.w * vb.w;
  v += __shfl_xor(v, 1, 16);
  v += __shfl_xor(v, 2, 16);
  v += __shfl_xor(v, 4, 16);
  v += __shfl_xor(v, 8, 16);
  if (l16 == 0) pred[e] = v;
}

__global__ void k_copy4(const float4* __restrict__ src, float4* __restrict__ dst, int n4) {
  int i = blockIdx.x * blockDim.x + threadIdx.x;
  if (i < n4) dst[i] = src[i];
}

}  // namespace

extern "C" void kernel_launch(void* const* d_in, const int* in_sizes, int n_in,
                              void* d_out, int out_size, void* d_ws, size_t ws_size,
                              hipStream_t stream) {
  (void)in_sizes; (void)n_in; (void)out_size; (void)ws_size;
  const float* x_pd = (const float*)d_in[0];
  const float* x_se = (const float*)d_in[1];
  const int* nid_pd = (const int*)d_in[2];
  const int* nid_se = (const int*)d_in[3];
  const int* eidx = (const int*)d_in[4];
  const int* elidx = (const int*)d_in[5];
  const float* elabel = (const float*)d_in[6];
  const float* W_pd = (const float*)d_in[7];
  const float* b_pd = (const float*)d_in[8];
  const float* W_se = (const float*)d_in[9];
  const float* b_se = (const float*)d_in[10];
  const float* emb_pd = (const float*)d_in[11];
  const float* emb_se = (const float*)d_in[12];
  const float* c1_p2s_Wl = (const float*)d_in[13];
  const float* c1_p2s_bl = (const float*)d_in[14];
  const float* c1_p2s_Wr = (const float*)d_in[15];
  const float* c1_s2p_Wl = (const float*)d_in[16];
  const float* c1_s2p_bl = (const float*)d_in[17];
  const float* c1_s2p_Wr = (const float*)d_in[18];
  const float* c2_p2s_Wl = (const float*)d_in[19];
  const float* c2_p2s_bl = (const float*)d_in[20];
  const float* c2_p2s_Wr = (const float*)d_in[21];
  const float* c2_s2p_Wl = (const float*)d_in[22];
  const float* c2_s2p_bl = (const float*)d_in[23];
  const float* c2_s2p_Wr = (const float*)d_in[24];

  const int* src = eidx;       // pd ids
  const int* dst = eidx + EC;  // se ids
  const int* li0 = elidx;      // pd ids
  const int* li1 = elidx + LC; // se ids

  char* ws = (char*)d_ws;
  size_t o = 0;
  auto alloc = [&](size_t bytes) -> char* {
    char* p = ws + o;
    o = (o + bytes + 255) & ~(size_t)255;
    return p;
  };
  float* h_pd = (float*)alloc((size_t)NP * 64 * 4);  // reused as pd2 in layer 2
  float* h_se = (float*)alloc((size_t)NS * 64 * 4);  // reused as se2 in layer 2
  float* pd1 = (float*)alloc((size_t)NP * 64 * 4);
  float* se1 = (float*)alloc((size_t)NS * 64 * 4);
  float* agg_pd = (float*)alloc((size_t)NP * 64 * 4);  // aliased as tmp pair arrays
  float* agg_se = (float*)alloc((size_t)NS * 64 * 4);
  int* col_se = (int*)alloc((size_t)EC * 4);
  int* col_pd = (int*)alloc((size_t)EC * 4);
  int* deg_se = (int*)alloc((size_t)NS * 4);
  int* deg_pd = (int*)alloc((size_t)NP * 4);
  int* rp_se = (int*)alloc((size_t)NS * 4);
  int* rp_pd = (int*)alloc((size_t)NP * 4);
  int* bcntS = (int*)alloc(1024);
  int* bcntP = (int*)alloc(1024);
  int* gbaseS = (int*)alloc(1024);
  int* gbaseP = (int*)alloc(1024);
  int* gcurS = (int*)alloc(1024);
  int* gcurP = (int*)alloc(1024);

  // temp (node, nbr) pair arrays alias agg_pd (dead until layer-1 agg):
  // 2 * EC * 8B = 25.6 MB == NP*64*4
  int2* tmpS = (int2*)agg_pd;
  int2* tmpP = tmpS + EC;

  hipMemsetAsync(bcntS, 0, 1024, stream);
  hipMemsetAsync(bcntP, 0, 1024, stream);

  // CSR build (bucketed counting sort; shared by both layers)
  k_bcount<<<NBLK, 256, 0, stream>>>(src, dst, bcntS, bcntP, EC);
  k_bscan<<<1, 256, 0, stream>>>(bcntS, bcntP, gbaseS, gbaseP, gcurS, gcurP);
  k_bscatter<<<NBLK, 256, 0, stream>>>(src, dst, gcurS, gcurP, tmpS, tmpP, EC);
  k_bfinal<64><<<NBS, 256, 0, stream>>>(tmpS, gbaseS, bcntS, SH_S, NS, rp_se, deg_se, col_se);
  k_bfinal<512><<<NBP, 256, 0, stream>>>(tmpP, gbaseP, bcntP, SH_P, NP, rp_pd, deg_pd, col_pd);

  // input projections
  k_proj<512><<<NP / 16, 256, 0, stream>>>(x_pd, W_pd, b_pd, emb_pd, nid_pd, h_pd, NP);
  k_proj<768><<<NS / 16, 256, 0, stream>>>(x_se, W_se, b_se, emb_se, nid_se, h_se, NS);

  // layer 1 (relu)
  k_agg<<<(NS + 3) / 4, 256, 0, stream>>>(h_pd, rp_se, deg_se, col_se, agg_se, NS);
  k_combine<true><<<NS / 16, 256, 0, stream>>>(agg_se, h_se, c1_p2s_Wl, c1_p2s_bl,
                                               c1_p2s_Wr, se1, NS);
  k_agg<<<(NP + 3) / 4, 256, 0, stream>>>(h_se, rp_pd, deg_pd, col_pd, agg_pd, NP);
  k_combine<true><<<NP / 16, 256, 0, stream>>>(agg_pd, h_pd, c1_s2p_Wl, c1_s2p_bl,
                                               c1_s2p_Wr, pd1, NP);

  // layer 2 (no act); outputs alias h buffers (dead after layer 1)
  float* se2 = h_se;
  float* pd2 = h_pd;
  k_agg<<<(NS + 3) / 4, 256, 0, stream>>>(pd1, rp_se, deg_se, col_se, agg_se, NS);
  k_combine<false><<<NS / 16, 256, 0, stream>>>(agg_se, se1, c2_p2s_Wl, c2_p2s_bl,
                                                c2_p2s_Wr, se2, NS);
  k_agg<<<(NP + 3) / 4, 256, 0, stream>>>(se1, rp_pd, deg_pd, col_pd, agg_pd, NP);
  k_combine<false><<<NP / 16, 256, 0, stream>>>(agg_pd, pd1, c2_s2p_Wl, c2_s2p_bl,
                                                c2_s2p_Wr, pd2, NP);

  // classifier + label passthrough
  float* outF = (float*)d_out;
  k_classify<<<(LC + 15) / 16, 256, 0, stream>>>(pd2, se2, li0, li1, outF, LC);
  k_copy4<<<(LC / 4 + 255) / 256, 256, 0, stream>>>((const float4*)elabel,
                                                    (float4*)(outF + LC), LC / 4);
}

// Round 4
// 860.841 us; speedup vs baseline: 1.5964x; 1.1884x over previous
//
#include <hip/hip_runtime.h>

namespace {

constexpr int NP = 100000;
constexpr int NS = 10000;
constexpr int EC = 1600000;
constexpr int LC = 1000000;

// bucketed CSR build params
constexpr int SH_S = 6;                        // se nodes per bucket = 64
constexpr int SH_P = 9;                        // pd nodes per bucket = 512
constexpr int NBS = (NS + 63) >> SH_S;         // 157 buckets
constexpr int NBP = (NP + 511) >> SH_P;        // 196 buckets
constexpr int CHUNK = 8192;
constexpr int NBLK = (EC + CHUNK - 1) / CHUNK; // 196

typedef short i16x8 __attribute__((ext_vector_type(8)));
typedef float f32x4 __attribute__((ext_vector_type(4)));

__device__ inline ushort f2bf(float f) {  // RNE fp32->bf16
  unsigned u = __float_as_uint(f);
  u += 0x7FFFu + ((u >> 16) & 1u);
  return (ushort)(u >> 16);
}

// ---------------- CSR build: bucketed counting sort ----------------

__global__ void __launch_bounds__(256) k_bcount(const int* __restrict__ src,
                                                const int* __restrict__ dst,
                                                int* __restrict__ bcntS,
                                                int* __restrict__ bcntP, int E) {
  __shared__ int hS[256];
  __shared__ int hP[256];
  const int t = threadIdx.x;
  hS[t] = 0;
  hP[t] = 0;
  __syncthreads();
  const int base = blockIdx.x * CHUNK;
  const int end = min(base + CHUNK, E);
  for (int e = base + t; e < end; e += 256) {
    atomicAdd(&hS[dst[e] >> SH_S], 1);
    atomicAdd(&hP[src[e] >> SH_P], 1);
  }
  __syncthreads();
  if (t < NBS && hS[t]) atomicAdd(&bcntS[t], hS[t]);
  if (t < NBP && hP[t]) atomicAdd(&bcntP[t], hP[t]);
}

__global__ void __launch_bounds__(256) k_bscan(const int* __restrict__ bcntS,
                                               const int* __restrict__ bcntP,
                                               int* __restrict__ gbaseS,
                                               int* __restrict__ gbaseP,
                                               int* __restrict__ gcurS,
                                               int* __restrict__ gcurP) {
  __shared__ int s[256];
  const int t = threadIdx.x;
  int v = (t < NBS) ? bcntS[t] : 0;
  s[t] = v;
  __syncthreads();
  for (int off = 1; off < 256; off <<= 1) {
    int u = (t >= off) ? s[t - off] : 0;
    __syncthreads();
    s[t] += u;
    __syncthreads();
  }
  if (t < NBS) {
    int ex = s[t] - v;
    gbaseS[t] = ex;
    gcurS[t] = ex;
  }
  __syncthreads();
  v = (t < NBP) ? bcntP[t] : 0;
  s[t] = v;
  __syncthreads();
  for (int off = 1; off < 256; off <<= 1) {
    int u = (t >= off) ? s[t - off] : 0;
    __syncthreads();
    s[t] += u;
    __syncthreads();
  }
  if (t < NBP) {
    int ex = s[t] - v;
    gbaseP[t] = ex;
    gcurP[t] = ex;
  }
}

__global__ void __launch_bounds__(256) k_bscatter(const int* __restrict__ src,
                                                  const int* __restrict__ dst,
                                                  int* __restrict__ gcurS,
                                                  int* __restrict__ gcurP,
                                                  int2* __restrict__ tmpS,
                                                  int2* __restrict__ tmpP, int E) {
  __shared__ int hS[256];
  __shared__ int hP[256];
  const int t = threadIdx.x;
  hS[t] = 0;
  hP[t] = 0;
  __syncthreads();
  const int base = blockIdx.x * CHUNK;
  const int end = min(base + CHUNK, E);
  for (int e = base + t; e < end; e += 256) {
    atomicAdd(&hS[dst[e] >> SH_S], 1);
    atomicAdd(&hP[src[e] >> SH_P], 1);
  }
  __syncthreads();
  int myBaseS = 0, myBaseP = 0;
  if (t < NBS) {
    int c = hS[t];
    myBaseS = c ? atomicAdd(&gcurS[t], c) : 0;
  }
  if (t < NBP) {
    int c = hP[t];
    myBaseP = c ? atomicAdd(&gcurP[t], c) : 0;
  }
  __syncthreads();
  if (t < NBS) hS[t] = myBaseS;
  if (t < NBP) hP[t] = myBaseP;
  __syncthreads();
  for (int e = base + t; e < end; e += 256) {
    const int d = dst[e];
    const int s = src[e];
    int p = atomicAdd(&hS[d >> SH_S], 1);
    tmpS[p] = make_int2(d, s);
    int q = atomicAdd(&hP[s >> SH_P], 1);
    tmpP[q] = make_int2(s, d);
  }
}

template <int NN>
__global__ void __launch_bounds__(256) k_bfinal(const int2* __restrict__ tmp,
                                                const int* __restrict__ gbase,
                                                const int* __restrict__ bcnt,
                                                int shift, int Nnodes,
                                                int* __restrict__ rowptr,
                                                int* __restrict__ deg,
                                                int* __restrict__ col) {
  __shared__ int ldeg[NN];
  __shared__ int lscan[512];
  const int b = blockIdx.x;
  const int t = threadIdx.x;
  const int n0 = b << shift;
  const int base = gbase[b];
  const int cnt = bcnt[b];
  for (int i = t; i < NN; i += 256) ldeg[i] = 0;
  __syncthreads();
  for (int j = t; j < cnt; j += 256) atomicAdd(&ldeg[tmp[base + j].x - n0], 1);
  __syncthreads();
  for (int i = t; i < 512; i += 256) lscan[i] = (i < NN) ? ldeg[i] : 0;
  __syncthreads();
  for (int off = 1; off < 512; off <<= 1) {
    const int i0 = t, i1 = t + 256;
    const int v0 = (i0 >= off) ? lscan[i0 - off] : 0;
    const int v1 = (i1 >= off) ? lscan[i1 - off] : 0;
    __syncthreads();
    lscan[i0] += v0;
    lscan[i1] += v1;
    __syncthreads();
  }
  for (int i = t; i < NN; i += 256) {
    const int n = n0 + i;
    if (n < Nnodes) {
      const int dg = ldeg[i];
      rowptr[n] = base + lscan[i] - dg;
      deg[n] = dg;
    }
  }
  __syncthreads();
  for (int i = t; i < NN; i += 256) lscan[i] -= ldeg[i];
  __syncthreads();
  for (int j = t; j < cnt; j += 256) {
    const int2 pr = tmp[base + j];
    const int p = atomicAdd(&lscan[pr.x - n0], 1);
    col[base + p] = pr.y;
  }
}

// ---------------- weight transpose+cvt prep: Wt[n][k] (bf16) = W[k][n] ----------------

struct WtJob {
  const float* src;  // [K][64] fp32
  ushort* dst;       // row n at dst + n*stride + off
  int K;
  int stride;
  int off;
};
struct WtJobs {
  WtJob j[10];
};

__global__ void __launch_bounds__(256) k_wt_all(WtJobs jobs) {
  int e = blockIdx.x * 256 + threadIdx.x;
#pragma unroll
  for (int i = 0; i < 10; i++) {
    const int K = jobs.j[i].K;
    const int sz = K * 64;
    if (e < sz) {
      const int n = e / K;
      const int k = e - n * K;
      jobs.j[i].dst[(size_t)n * jobs.j[i].stride + jobs.j[i].off + k] =
          f2bf(jobs.j[i].src[(size_t)k * 64 + n]);
      return;
    }
    e -= sz;
  }
}

// ---------------- MFMA GEMM: out[M x 64] = act(A[M x K] @ W[K x 64] + bias (+ emb)) ----
// A = A0 (cols 0..KA0) | A1 (cols KA0..K), fp32, converted to bf16 inline.
// Wt: bf16, [64 n][K k] row-major (pre-transposed).
// Block: 256 thr = 4 waves; 64 rows x 64 cols per block; K-step 64.

template <bool RELU, bool EMB>
__global__ void __launch_bounds__(256) k_mgemm(const float* __restrict__ A0,
                                               const float* __restrict__ A1, int KA0,
                                               int sA0, int sA1, int K,
                                               const ushort* __restrict__ Wt,
                                               const float* __restrict__ bias,
                                               const float* __restrict__ emb,
                                               const int* __restrict__ nid,
                                               float* __restrict__ out, int M) {
  __shared__ ushort Xs[64 * 72];
  __shared__ ushort Ws[64 * 72];
  const int t = threadIdx.x;
  const int row0 = blockIdx.x * 64;
  const int lane = t & 63;
  const int w = t >> 6;
  const int m16 = lane & 15;
  const int q = lane >> 4;

  f32x4 acc[4];
#pragma unroll
  for (int nt = 0; nt < 4; nt++) acc[nt] = {0.f, 0.f, 0.f, 0.f};

  const int ksteps = K >> 6;
  for (int ks = 0; ks < ksteps; ks++) {
    const int k0 = ks << 6;
    // prefetch to regs
    float4 xv[4];
#pragma unroll
    for (int i = 0; i < 4; i++) {
      const int u = t + i * 256;
      const int row = u >> 4;
      const int k4 = (u & 15) << 2;
      const int gr = min(row0 + row, M - 1);
      const int kk = k0 + k4;
      const float* sp = (kk < KA0) ? (A0 + (size_t)gr * sA0 + kk)
                                   : (A1 + (size_t)gr * sA1 + (kk - KA0));
      xv[i] = *reinterpret_cast<const float4*>(sp);
    }
    uint4 wv[2];
#pragma unroll
    for (int i = 0; i < 2; i++) {
      const int u = t + i * 256;
      const int n = u >> 3;
      const int kk8 = (u & 7) << 3;
      wv[i] = *reinterpret_cast<const uint4*>(Wt + (size_t)n * K + k0 + kk8);
    }
    __syncthreads();
#pragma unroll
    for (int i = 0; i < 4; i++) {
      const int u = t + i * 256;
      const int row = u >> 4;
      const int k4 = (u & 15) << 2;
      ushort4 o;
      o.x = f2bf(xv[i].x);
      o.y = f2bf(xv[i].y);
      o.z = f2bf(xv[i].z);
      o.w = f2bf(xv[i].w);
      *reinterpret_cast<ushort4*>(&Xs[row * 72 + k4]) = o;
    }
#pragma unroll
    for (int i = 0; i < 2; i++) {
      const int u = t + i * 256;
      const int n = u >> 3;
      const int kk8 = (u & 7) << 3;
      *reinterpret_cast<uint4*>(&Ws[n * 72 + kk8]) = wv[i];
    }
    __syncthreads();

    const ushort* ap = &Xs[(w * 16 + m16) * 72 + q * 8];
    const i16x8 a0 = *reinterpret_cast<const i16x8*>(ap);
    const i16x8 a1 = *reinterpret_cast<const i16x8*>(ap + 32);
#pragma unroll
    for (int nt = 0; nt < 4; nt++) {
      const ushort* bp = &Ws[(nt * 16 + m16) * 72 + q * 8];
      const i16x8 b0 = *reinterpret_cast<const i16x8*>(bp);
      const i16x8 b1 = *reinterpret_cast<const i16x8*>(bp + 32);
      acc[nt] = __builtin_amdgcn_mfma_f32_16x16x32_bf16(a0, b0, acc[nt], 0, 0, 0);
      acc[nt] = __builtin_amdgcn_mfma_f32_16x16x32_bf16(a1, b1, acc[nt], 0, 0, 0);
    }
  }

  // epilogue: C/D layout col=lane&15, row=q*4+reg
  int grow[4];
  int nrow[4];
#pragma unroll
  for (int r = 0; r < 4; r++) {
    grow[r] = row0 + w * 16 + q * 4 + r;
    nrow[r] = (EMB && grow[r] < M) ? nid[grow[r]] : 0;
  }
#pragma unroll
  for (int nt = 0; nt < 4; nt++) {
    const int colv = nt * 16 + m16;
    const float bv = bias[colv];
#pragma unroll
    for (int r = 0; r < 4; r++) {
      if (grow[r] < M) {
        float v = acc[nt][r] + bv;
        if (EMB) v += emb[(size_t)nrow[r] * 64 + colv];
        if (RELU) v = fmaxf(v, 0.f);
        out[(size_t)grow[r] * 64 + colv] = v;
      }
    }
  }
}

// ---------------- aggregation: mean over CSR neighbors ----------------

__global__ void __launch_bounds__(256) k_agg(const float* __restrict__ h,
                                             const int* __restrict__ rowptr,
                                             const int* __restrict__ deg,
                                             const int* __restrict__ col,
                                             float* __restrict__ mean, int n_dst) {
  const int node = blockIdx.x * 4 + (threadIdx.x >> 6);
  const int lane = threadIdx.x & 63;
  if (node >= n_dst) return;
  const int beg = rowptr[node];
  const int cnt = deg[node];
  float acc = 0.f;
  int j = 0;
  for (; j + 8 <= cnt; j += 8) {
    int n0 = col[beg + j + 0], n1 = col[beg + j + 1];
    int n2 = col[beg + j + 2], n3 = col[beg + j + 3];
    int n4 = col[beg + j + 4], n5 = col[beg + j + 5];
    int n6 = col[beg + j + 6], n7 = col[beg + j + 7];
    float a0 = h[(size_t)n0 * 64 + lane];
    float a1 = h[(size_t)n1 * 64 + lane];
    float a2 = h[(size_t)n2 * 64 + lane];
    float a3 = h[(size_t)n3 * 64 + lane];
    float a4 = h[(size_t)n4 * 64 + lane];
    float a5 = h[(size_t)n5 * 64 + lane];
    float a6 = h[(size_t)n6 * 64 + lane];
    float a7 = h[(size_t)n7 * 64 + lane];
    acc += ((a0 + a1) + (a2 + a3)) + ((a4 + a5) + (a6 + a7));
  }
  for (; j < cnt; ++j) acc += h[(size_t)col[beg + j] * 64 + lane];
  const float d = (cnt > 0) ? (float)cnt : 1.f;
  mean[(size_t)node * 64 + lane] = acc / d;
}

// ---------------- classifier ----------------

__global__ void __launch_bounds__(256) k_classify(const float* __restrict__ pd2,
                                                  const float* __restrict__ se2,
                                                  const int* __restrict__ i0,
                                                  const int* __restrict__ i1,
                                                  float* __restrict__ pred, int L) {
  const int e = blockIdx.x * 16 + (threadIdx.x >> 4);
  if (e >= L) return;
  const int l16 = threadIdx.x & 15;
  const int a = i0[e];
  const int b = i1[e];
  const float4 va = *reinterpret_cast<const float4*>(&pd2[(size_t)a * 64 + l16 * 4]);
  const float4 vb = *reinterpret_cast<const float4*>(&se2[(size_t)b * 64 + l16 * 4]);
  float v = va.x * vb.x + va.y * vb.y + va.z * vb.z + va.w * vb.w;
  v += __shfl_xor(v, 1, 16);
  v += __shfl_xor(v, 2, 16);
  v += __shfl_xor(v, 4, 16);
  v += __shfl_xor(v, 8, 16);
  if (l16 == 0) pred[e] = v;
}

__global__ void k_copy4(const float4* __restrict__ src, float4* __restrict__ dst, int n4) {
  int i = blockIdx.x * blockDim.x + threadIdx.x;
  if (i < n4) dst[i] = src[i];
}

}  // namespace

extern "C" void kernel_launch(void* const* d_in, const int* in_sizes, int n_in,
                              void* d_out, int out_size, void* d_ws, size_t ws_size,
                              hipStream_t stream) {
  (void)in_sizes; (void)n_in; (void)out_size; (void)ws_size;
  const float* x_pd = (const float*)d_in[0];
  const float* x_se = (const float*)d_in[1];
  const int* nid_pd = (const int*)d_in[2];
  const int* nid_se = (const int*)d_in[3];
  const int* eidx = (const int*)d_in[4];
  const int* elidx = (const int*)d_in[5];
  const float* elabel = (const float*)d_in[6];
  const float* W_pd = (const float*)d_in[7];
  const float* b_pd = (const float*)d_in[8];
  const float* W_se = (const float*)d_in[9];
  const float* b_se = (const float*)d_in[10];
  const float* emb_pd = (const float*)d_in[11];
  const float* emb_se = (const float*)d_in[12];
  const float* c1_p2s_Wl = (const float*)d_in[13];
  const float* c1_p2s_bl = (const float*)d_in[14];
  const float* c1_p2s_Wr = (const float*)d_in[15];
  const float* c1_s2p_Wl = (const float*)d_in[16];
  const float* c1_s2p_bl = (const float*)d_in[17];
  const float* c1_s2p_Wr = (const float*)d_in[18];
  const float* c2_p2s_Wl = (const float*)d_in[19];
  const float* c2_p2s_bl = (const float*)d_in[20];
  const float* c2_p2s_Wr = (const float*)d_in[21];
  const float* c2_s2p_Wl = (const float*)d_in[22];
  const float* c2_s2p_bl = (const float*)d_in[23];
  const float* c2_s2p_Wr = (const float*)d_in[24];

  const int* src = eidx;       // pd ids
  const int* dst = eidx + EC;  // se ids
  const int* li0 = elidx;      // pd ids
  const int* li1 = elidx + LC; // se ids

  char* ws = (char*)d_ws;
  size_t o = 0;
  auto alloc = [&](size_t bytes) -> char* {
    char* p = ws + o;
    o = (o + bytes + 255) & ~(size_t)255;
    return p;
  };
  float* h_pd = (float*)alloc((size_t)NP * 64 * 4);  // reused as pd2 in layer 2
  float* h_se = (float*)alloc((size_t)NS * 64 * 4);  // reused as se2 in layer 2
  float* pd1 = (float*)alloc((size_t)NP * 64 * 4);
  float* se1 = (float*)alloc((size_t)NS * 64 * 4);
  float* agg_pd = (float*)alloc((size_t)NP * 64 * 4);  // aliased as tmp pair arrays
  float* agg_se = (float*)alloc((size_t)NS * 64 * 4);
  int* col_se = (int*)alloc((size_t)EC * 4);
  int* col_pd = (int*)alloc((size_t)EC * 4);
  int* deg_se = (int*)alloc((size_t)NS * 4);
  int* deg_pd = (int*)alloc((size_t)NP * 4);
  int* rp_se = (int*)alloc((size_t)NS * 4);
  int* rp_pd = (int*)alloc((size_t)NP * 4);
  int* bcntS = (int*)alloc(1024);
  int* bcntP = (int*)alloc(1024);
  int* gbaseS = (int*)alloc(1024);
  int* gbaseP = (int*)alloc(1024);
  int* gcurS = (int*)alloc(1024);
  int* gcurP = (int*)alloc(1024);
  ushort* wt_pd = (ushort*)alloc((size_t)64 * 512 * 2);
  ushort* wt_se = (ushort*)alloc((size_t)64 * 768 * 2);
  ushort* wt_c1p2s = (ushort*)alloc((size_t)64 * 128 * 2);
  ushort* wt_c1s2p = (ushort*)alloc((size_t)64 * 128 * 2);
  ushort* wt_c2p2s = (ushort*)alloc((size_t)64 * 128 * 2);
  ushort* wt_c2s2p = (ushort*)alloc((size_t)64 * 128 * 2);

  // temp (node, nbr) pair arrays alias agg_pd (dead until layer-1 agg)
  int2* tmpS = (int2*)agg_pd;
  int2* tmpP = tmpS + EC;

  hipMemsetAsync(bcntS, 0, 1024, stream);
  hipMemsetAsync(bcntP, 0, 1024, stream);

  // CSR build (bucketed counting sort; shared by both layers)
  k_bcount<<<NBLK, 256, 0, stream>>>(src, dst, bcntS, bcntP, EC);
  k_bscan<<<1, 256, 0, stream>>>(bcntS, bcntP, gbaseS, gbaseP, gcurS, gcurP);
  k_bscatter<<<NBLK, 256, 0, stream>>>(src, dst, gcurS, gcurP, tmpS, tmpP, EC);
  k_bfinal<64><<<NBS, 256, 0, stream>>>(tmpS, gbaseS, bcntS, SH_S, NS, rp_se, deg_se, col_se);
  k_bfinal<512><<<NBP, 256, 0, stream>>>(tmpP, gbaseP, bcntP, SH_P, NP, rp_pd, deg_pd, col_pd);

  // weight transpose + bf16 cvt (10 jobs, one kernel)
  {
    WtJobs jobs;
    jobs.j[0] = {W_pd, wt_pd, 512, 512, 0};
    jobs.j[1] = {W_se, wt_se, 768, 768, 0};
    jobs.j[2] = {c1_p2s_Wl, wt_c1p2s, 64, 128, 0};
    jobs.j[3] = {c1_p2s_Wr, wt_c1p2s, 64, 128, 64};
    jobs.j[4] = {c1_s2p_Wl, wt_c1s2p, 64, 128, 0};
    jobs.j[5] = {c1_s2p_Wr, wt_c1s2p, 64, 128, 64};
    jobs.j[6] = {c2_p2s_Wl, wt_c2p2s, 64, 128, 0};
    jobs.j[7] = {c2_p2s_Wr, wt_c2p2s, 64, 128, 64};
    jobs.j[8] = {c2_s2p_Wl, wt_c2s2p, 64, 128, 0};
    jobs.j[9] = {c2_s2p_Wr, wt_c2s2p, 64, 128, 64};
    const int tot = 64 * (512 + 768 + 8 * 64);
    k_wt_all<<<(tot + 255) / 256, 256, 0, stream>>>(jobs);
  }

  const int gP = (NP + 63) / 64;  // 1563
  const int gS = (NS + 63) / 64;  // 157

  // input projections (MFMA): h = x @ W + b + emb[nid]
  k_mgemm<false, true><<<gP, 256, 0, stream>>>(x_pd, nullptr, 512, 512, 0, 512, wt_pd,
                                               b_pd, emb_pd, nid_pd, h_pd, NP);
  k_mgemm<false, true><<<gS, 256, 0, stream>>>(x_se, nullptr, 768, 768, 0, 768, wt_se,
                                               b_se, emb_se, nid_se, h_se, NS);

  // layer 1 (relu): out = [mean | xd] @ [Wl;Wr] + bl
  k_agg<<<(NS + 3) / 4, 256, 0, stream>>>(h_pd, rp_se, deg_se, col_se, agg_se, NS);
  k_mgemm<true, false><<<gS, 256, 0, stream>>>(agg_se, h_se, 64, 64, 64, 128, wt_c1p2s,
                                               c1_p2s_bl, nullptr, nullptr, se1, NS);
  k_agg<<<(NP + 3) / 4, 256, 0, stream>>>(h_se, rp_pd, deg_pd, col_pd, agg_pd, NP);
  k_mgemm<true, false><<<gP, 256, 0, stream>>>(agg_pd, h_pd, 64, 64, 64, 128, wt_c1s2p,
                                               c1_s2p_bl, nullptr, nullptr, pd1, NP);

  // layer 2 (no act); outputs alias h buffers (dead after layer 1)
  float* se2 = h_se;
  float* pd2 = h_pd;
  k_agg<<<(NS + 3) / 4, 256, 0, stream>>>(pd1, rp_se, deg_se, col_se, agg_se, NS);
  k_mgemm<false, false><<<gS, 256, 0, stream>>>(agg_se, se1, 64, 64, 64, 128, wt_c2p2s,
                                                c2_p2s_bl, nullptr, nullptr, se2, NS);
  k_agg<<<(NP + 3) / 4, 256, 0, stream>>>(se1, rp_pd, deg_pd, col_pd, agg_pd, NP);
  k_mgemm<false, false><<<gP, 256, 0, stream>>>(agg_pd, pd1, 64, 64, 64, 128, wt_c2s2p,
                                                c2_s2p_bl, nullptr, nullptr, pd2, NP);

  // classifier + label passthrough
  float* outF = (float*)d_out;
  k_classify<<<(LC + 15) / 16, 256, 0, stream>>>(pd2, se2, li0, li1, outF, LC);
  k_copy4<<<(LC / 4 + 255) / 256, 256, 0, stream>>>((const float4*)elabel,
                                                    (float4*)(outF + LC), LC / 4);
}